// Round 3
// baseline (3140.150 us; speedup 1.0000x reference)
//
#include <hip/hip_runtime.h>
#include <cstdint>
#include <math.h>

#define NPTS 8192
#define NB 4
#define NG 2048
#define NK 32
#define CIN 96
#define COUT 192

typedef float v2f __attribute__((ext_vector_type(2)));

// ---------------- setup: SoA transpose + |p|^2 (bit-exact vs ref dst2) ----------------
__global__ __launch_bounds__(256) void setup_kernel(const float* __restrict__ xyz,
                                                    float* __restrict__ xs, float* __restrict__ ys,
                                                    float* __restrict__ zs, float* __restrict__ d2){
  int i = blockIdx.x*256 + threadIdx.x;
  if (i >= NB*NPTS) return;
  float x = xyz[3*i+0], y = xyz[3*i+1], z = xyz[3*i+2];
  xs[i]=x; ys[i]=y; zs[i]=z;
  d2[i] = __fadd_rn(__fadd_rn(__fmul_rn(x,x),__fmul_rn(y,y)),__fmul_rn(z,z));
}

// ---------------- FPS: one block per batch, 2047 serial rounds ----------------
// Per round: packed-fp32 distance update, wave shfl-reduce, per-wave LDS slot
// (double-buffered, ONE barrier), redundant 16-key reduce in every wave.
__global__ __launch_bounds__(1024) void fps_kernel(const float* __restrict__ xyz, int* __restrict__ fps_idx){
#pragma clang fp contract(off)   // selection-critical: no fma contraction anywhere here
  __shared__ unsigned long long wk[2][16];
  const int b = blockIdx.x;
  const int t = threadIdx.x;
  const int wid = t>>6, lane = t&63;
  const float* base = xyz + (size_t)b*NPTS*3;
  // pair layout: px[j].x = point t+1024*(2j), px[j].y = point t+1024*(2j+1)
  v2f px[4], py[4], pz[4], D[4];
#pragma unroll
  for (int j=0;j<4;++j){
    int p0 = t + 2048*j, p1 = p0 + 1024;
    px[j] = (v2f){ base[3*p0+0], base[3*p1+0] };
    py[j] = (v2f){ base[3*p0+1], base[3*p1+1] };
    pz[j] = (v2f){ base[3*p0+2], base[3*p1+2] };
    D[j]  = (v2f){ 1e10f, 1e10f };                 // ref init
  }
  if (t==0) fps_idx[b*NG] = 0;
  float lx = base[0], ly = base[1], lz = base[2];  // seed = point 0
  for (int it=0; it<NG-1; ++it){
    float bd=-1.0f; int bj=0;
#pragma unroll
    for (int j=0;j<4;++j){
      v2f dx = px[j]-lx, dy = py[j]-ly, dz = pz[j]-lz;
      v2f s = (dx*dx + dy*dy) + dz*dz;             // contract(off): pk_mul/pk_add, IEEE rn
      v2f nd = __builtin_elementwise_min(D[j], s);
      D[j] = nd;
      if (nd.x > bd){ bd=nd.x; bj=2*j;   }         // ascending jj, strict >: lowest idx on tie
      if (nd.y > bd){ bd=nd.y; bj=2*j+1; }
    }
    const int bp = t + (bj<<10);                   // flat point index
    // pack (dist_bits, ~idx): u64-max == np.argmax incl. lowest-index tie-break
    unsigned long long key = (((unsigned long long)__float_as_uint(bd))<<32)
                           | (unsigned long long)(unsigned)(~bp);
#pragma unroll
    for (int off=32; off>0; off>>=1){
      unsigned long long ok = __shfl_xor(key, off);
      if (ok > key) key = ok;
    }
    if (lane==0) wk[it&1][wid] = key;
    __syncthreads();                               // ONE barrier per round (wk double-buffered)
    unsigned long long k2 = wk[it&1][lane & 15];
#pragma unroll
    for (int off=8; off>0; off>>=1){
      unsigned long long ok = __shfl_xor(k2, off);
      if (ok > k2) k2 = ok;
    }
    int pw = __builtin_amdgcn_readfirstlane((int)(~(unsigned)(k2 & 0xffffffffULL)));
    if (t==0) fps_idx[b*NG + it + 1] = pw;
    // winner coords: wave-uniform scalar load (L1/L2-resident, 96 KB/batch)
    lx = base[3*pw+0]; ly = base[3*pw+1]; lz = base[3*pw+2];
  }
}

// ---------------- kNN: wave-wide exact top-32 (lexicographic (d,idx)) ----------------
__device__ __forceinline__ bool lexlt(float ad, int ai, float bd, int bi){
  return (ad < bd) || ((ad == bd) && (ai < bi));
}
__device__ __forceinline__ void sort_desc(float& d, int& i, int lane){
#pragma unroll
  for (int k=2;k<=64;k<<=1){
#pragma unroll
    for (int j=k>>1;j>0;j>>=1){
      float od = __shfl_xor(d, j);
      int   oi = __shfl_xor(i, j);
      bool dirUp = (lane & k) != 0;      // flipped -> overall descending
      bool lower = (lane & j) == 0;
      bool less  = lexlt(d,i,od,oi);
      bool keep  = (less == (lower == dirUp));
      if (!keep){ d=od; i=oi; }
    }
  }
}
__device__ __forceinline__ void merge_asc(float& d, int& i, int lane){
#pragma unroll
  for (int j=32;j>0;j>>=1){
    float od = __shfl_xor(d, j);
    int   oi = __shfl_xor(i, j);
    bool lower = (lane & j) == 0;
    bool less  = lexlt(d,i,od,oi);
    bool keep  = (less == lower);
    if (!keep){ d=od; i=oi; }
  }
}

__global__ __launch_bounds__(256) void knn_kernel(const float* __restrict__ xs, const float* __restrict__ ys,
                                                  const float* __restrict__ zs, const float* __restrict__ d2,
                                                  const int* __restrict__ fps_idx, int* __restrict__ knn_out){
  __shared__ float tx[256], ty[256], tz[256], td[256];
  const int tid = threadIdx.x;
  const int wid = tid>>6, lane = tid&63;
  const int pid = blockIdx.x*4 + wid;     // b*NG+g
  const int b = pid >> 11;
  const float* bx = xs + b*NPTS;
  const float* by = ys + b*NPTS;
  const float* bz = zs + b*NPTS;
  const float* bD = d2 + b*NPTS;
  const int fi = fps_idx[pid];
  const float ax = bx[fi], ay = by[fi], az = bz[fi];
  const float src2 = __fadd_rn(__fadd_rn(__fmul_rn(ax,ax),__fmul_rn(ay,ay)),__fmul_rn(az,az));
  float Ad = INFINITY; int Ai = 0x7fffffff;      // sorted-ascending top-64 (1/lane)
  float tau_d = INFINITY; int tau_i = 0x7fffffff; // current exact 32nd smallest
  for (int s=0; s<NPTS/256; ++s){
    __syncthreads();
    int gidx = s*256 + tid;
    tx[tid]=bx[gidx]; ty[tid]=by[gidx]; tz[tid]=bz[gidx]; td[tid]=bD[gidx];
    __syncthreads();
    float m0,m1,m2,m3; int i0,i1,i2,i3;
#define LOADJ(mj, ij, J) { int li = (J)*64 + lane; \
    float dot = __fadd_rn(__fadd_rn(__fmul_rn(ax,tx[li]),__fmul_rn(ay,ty[li])),__fmul_rn(az,tz[li])); \
    mj = __fadd_rn(__fadd_rn(__fmul_rn(-2.0f,dot), src2), td[li]); ij = s*256 + li; }
    LOADJ(m0,i0,0) LOADJ(m1,i1,1) LOADJ(m2,i2,2) LOADJ(m3,i3,3)
#undef LOADJ
    while (true){
      bool any = lexlt(m0,i0,tau_d,tau_i) || lexlt(m1,i1,tau_d,tau_i) ||
                 lexlt(m2,i2,tau_d,tau_i) || lexlt(m3,i3,tau_d,tau_i);
      if (__ballot(any) == 0ull) break;
      float cd = m0; int ci = i0; int sel = 0;
      if (lexlt(m1,i1,cd,ci)){ cd=m1; ci=i1; sel=1; }
      if (lexlt(m2,i2,cd,ci)){ cd=m2; ci=i2; sel=2; }
      if (lexlt(m3,i3,cd,ci)){ cd=m3; ci=i3; sel=3; }
      if      (sel==0) m0=INFINITY;
      else if (sel==1) m1=INFINITY;
      else if (sel==2) m2=INFINITY;
      else             m3=INFINITY;
      sort_desc(cd, ci, lane);                    // new chunk descending
      if (lexlt(cd,ci,Ad,Ai)){ Ad=cd; Ai=ci; }    // elementwise min -> bitonic
      merge_asc(Ad, Ai, lane);                    // re-sort ascending
      tau_d = __shfl(Ad, 31);
      tau_i = __shfl(Ai, 31);
    }
  }
  if (lane < NK) knn_out[pid*NK + lane] = Ai;
}

// ---------------- global stats (fp64 partials per block) ----------------
__global__ __launch_bounds__(256) void stats_kernel(const float* __restrict__ x, const float* __restrict__ xyz,
                                                    const int* __restrict__ fps_idx, const int* __restrict__ knn,
                                                    double* __restrict__ partials){
  const int tid=threadIdx.x, wid=tid>>6, lane=tid&63;
  const int pid = blockIdx.x*4 + wid;
  const int b = pid>>11;
  const int fi = fps_idx[pid];
  const float* xb = x + (size_t)b*NPTS*CIN;
  const float* zb = xyz + (size_t)b*NPTS*3;
  const float lc0 = xb[fi*CIN + lane];
  float lc1 = 0.f; if (lane<32) lc1 = xb[fi*CIN + 64 + lane];
  float czv = 0.f; if (lane<3)  czv = zb[fi*3 + lane];
  double s1=0.0, s2=0.0, a1=0.0, a2=0.0;
  for (int k=0;k<NK;++k){
    int idx = knn[pid*NK + k];
    float d0 = __fsub_rn(xb[idx*CIN + lane], lc0);
    s1 += (double)d0; s2 += (double)d0*(double)d0;
    if (lane<32){
      float d1 = __fsub_rn(xb[idx*CIN + 64 + lane], lc1);
      s1 += (double)d1; s2 += (double)d1*(double)d1;
    }
    if (lane<3){
      float w = __fsub_rn(zb[idx*3 + lane], czv);
      a1 += (double)w; a2 += (double)w*(double)w;
    }
  }
#pragma unroll
  for (int off=32; off>0; off>>=1){ s1 += __shfl_xor(s1,off); s2 += __shfl_xor(s2,off); }
  __shared__ double shx[4][2];
  __shared__ double shz[4][3][2];
  if (lane==0){ shx[wid][0]=s1; shx[wid][1]=s2; }
  if (lane<3){ shz[wid][lane][0]=a1; shz[wid][lane][1]=a2; }
  __syncthreads();
  if (tid==0){
    double u0=0,u1=0;
    for (int w=0;w<4;++w){ u0+=shx[w][0]; u1+=shx[w][1]; }
    double* outp = partials + (size_t)blockIdx.x*8;
    outp[0]=u0; outp[1]=u1;
    for (int axq=0; axq<3; ++axq){
      double v0=0,v1=0;
      for (int w=0;w<4;++w){ v0+=shz[w][axq][0]; v1+=shz[w][axq][1]; }
      outp[2+2*axq]=v0; outp[3+2*axq]=v1;
    }
  }
}

__global__ void finalize_kernel(const double* __restrict__ partials, float* __restrict__ scal){
  const int lane = threadIdx.x;  // 64 threads, 1 wave
  double s1=0,s2=0;
  double z0a=0,z0b=0,z1a=0,z1b=0,z2a=0,z2b=0;
  for (int i=0;i<32;++i){
    const double* p = partials + (size_t)(lane*32+i)*8;   // 32 consecutive blocks -> same b
    s1+=p[0]; s2+=p[1];
    z0a+=p[2]; z0b+=p[3]; z1a+=p[4]; z1b+=p[5]; z2a+=p[6]; z2b+=p[7];
  }
#pragma unroll
  for (int off=32; off>0; off>>=1){ s1+=__shfl_xor(s1,off); s2+=__shfl_xor(s2,off); }
#pragma unroll
  for (int off=8; off>0; off>>=1){
    z0a+=__shfl_xor(z0a,off); z0b+=__shfl_xor(z0b,off);
    z1a+=__shfl_xor(z1a,off); z1b+=__shfl_xor(z1b,off);
    z2a+=__shfl_xor(z2a,off); z2b+=__shfl_xor(z2b,off);
  }
  __shared__ double zb[4][3][2];
  if ((lane&15)==0){
    int b = lane>>4;
    zb[b][0][0]=z0a; zb[b][0][1]=z0b;
    zb[b][1][0]=z1a; zb[b][1][1]=z1b;
    zb[b][2][0]=z2a; zb[b][2][1]=z2b;
  }
  __syncthreads();
  if (lane==0){
    double nx = (double)NB*NG*NK*CIN;
    double varx = (s2 - s1*s1/nx)/(nx-1.0);
    float stdx = (float)sqrt(varx);
    double t1=0,t2=0;
    for (int b=0;b<4;++b) for (int a=0;a<3;++a){ t1+=zb[b][a][0]; t2+=zb[b][a][1]; }
    double nz = (double)NB*NG*NK*3;
    double varz = (t2 - t1*t1/nz)/(nz-1.0);
    float stdz = (float)sqrt(varz);
    float sdiv = stdz + 1e-5f;
    double n2 = (double)NG*NK;
    double acc=0.0;
    for (int b=0;b<4;++b) for (int a=0;a<3;++a){
      double v = (zb[b][a][1] - zb[b][a][0]*zb[b][a][0]/n2)/(n2-1.0);
      acc += sqrt(v);
    }
    float gstd = (float)(acc/12.0) / sdiv;   // std(x4) = std(raw)/(std_xyz+1e-5)
    float sig = 0.26f*(1.0f+gstd) + 1e-6f;
    float blend = 1.0f/(1.0f + expf(-(gstd-0.1f)*10.0f));
    scal[0] = 1.0f/(stdx + 1e-5f);
    scal[1] = 1.0f/sdiv;
    scal[2] = 1.0f/sig;
    scal[3] = blend;
  }
}

// ---------------- main fused kernel: pe + weighting + max/mean over K -> lc in d_out ----------------
__global__ __launch_bounds__(256) void main_kernel(const float* __restrict__ x, const float* __restrict__ xyz,
                                                   const int* __restrict__ fps_idx, const int* __restrict__ knn,
                                                   const float* __restrict__ scal, float* __restrict__ lc_out){
  const int tid=threadIdx.x, wid=tid>>6, lane=tid&63;
  const int pid = blockIdx.x*4 + wid;
  const int b = pid>>11, g = pid&2047;
  const float inv_x = scal[0], inv_z = scal[1], inv_sig = scal[2], blend = scal[3];
  const float omb = 1.0f - blend;
  const int fi = fps_idx[pid];
  const float* xb = x + (size_t)b*NPTS*CIN;
  const float* zb = xyz + (size_t)b*NPTS*3;
  const float cx = zb[fi*3+0], cy = zb[fi*3+1], cz = zb[fi*3+2];
  // lane's 3 channels: c = lane, 64+lane, 128+lane
  const float lcx0 = xb[fi*CIN + lane];
  const float lcx1 = (lane<32) ? xb[fi*CIN + 64 + lane] : xb[fi*CIN + lane - 32];
  const float lcx2 = xb[fi*CIN + 32 + lane];
  // r0: fourier, dim = lane>>5 (0/1), rr = lane&31, freq = rr>>1, odd->cos
  const int dim0 = lane>>5;
  const int rr0 = lane&31;
  const bool cos0 = rr0 & 1;
  const float bs0 = 100.0f / powf(1000.0f, (float)(rr0>>1) * (1.0f/16.0f));
  // r1: lane<32 fourier dim=2; lane>=32 adaptive dim=0, j=lane-32
  const bool cos1 = lane & 1;
  const float bs1 = 100.0f / powf(1000.0f, (float)((lane&31)>>1) * (1.0f/16.0f));
  const float fv1 = (float)(-1.0 + 2.0*(double)(lane-32+1)/33.0);
  // r2: adaptive, cc=32+lane: dim=cc>>5 (1/2), j=cc&31
  const int dim2 = (32+lane)>>5;
  const int j2 = (32+lane)&31;
  const float fv2 = (float)(-1.0 + 2.0*(double)(j2+1)/33.0);

  float mx0=-INFINITY, mx1=-INFINITY, mx2=-INFINITY;
  float sm0=0.f, sm1=0.f, sm2=0.f;
  for (int k=0;k<NK;++k){
    const int idx = knn[pid*NK + k];
    const float p0 = zb[idx*3+0], p1 = zb[idx*3+1], p2v = zb[idx*3+2];
    const float xn0 = (p0-cx)*inv_z, xn1 = (p1-cy)*inv_z, xn2 = (p2v-cz)*inv_z;
    const float xk0 = xb[idx*CIN + lane];
    float xk1 = 0.f; if (lane<32) xk1 = xb[idx*CIN + 64 + lane];
    { // r0
      float v = dim0 ? xn1 : xn0;
      float a = v * bs0;
      float pe = cos0 ? __cosf(a) : __sinf(a);
      float f = (xk0 - lcx0) * inv_x;
      float w = (f + pe) * pe;
      mx0 = fmaxf(mx0, w); sm0 += w;
    }
    { // r1
      float pe, f;
      if (lane < 32){
        float a = xn2 * bs1;
        pe = cos1 ? __cosf(a) : __sinf(a);
        f = (xk1 - lcx1) * inv_x;
      } else {
        float zq = (xn0 - fv1) * inv_sig;
        pe = blend * __expf(-0.5f*zq*zq) + omb * __cosf(zq);
        f = lcx1;   // raw center features (second concat half)
      }
      float w = (f + pe) * pe;
      mx1 = fmaxf(mx1, w); sm1 += w;
    }
    { // r2
      float v = (dim2==1) ? xn1 : xn2;
      float zq = (v - fv2) * inv_sig;
      float pe = blend * __expf(-0.5f*zq*zq) + omb * __cosf(zq);
      float w = (lcx2 + pe) * pe;
      mx2 = fmaxf(mx2, w); sm2 += w;
    }
  }
  const size_t obase = ((size_t)b*COUT)*NG + g;
  lc_out[obase + (size_t)lane*NG]       = mx0 + sm0*(1.0f/32.0f);
  lc_out[obase + (size_t)(64+lane)*NG]  = mx1 + sm1*(1.0f/32.0f);
  lc_out[obase + (size_t)(128+lane)*NG] = mx2 + sm2*(1.0f/32.0f);
}

// ---------------- batch-norm stats (per channel over B,G; ddof=0) ----------------
__global__ __launch_bounds__(256) void bn_stats_kernel(const float* __restrict__ lc, float* __restrict__ bn){
  const int c = blockIdx.x, t = threadIdx.x, lane=t&63, wid=t>>6;
  double s1=0.0, s2=0.0;
  for (int i=t; i<NB*NG; i+=256){
    int b=i>>11, g=i&2047;
    float v = lc[((size_t)(b*COUT)+c)*NG + g];
    s1 += (double)v; s2 += (double)v*(double)v;
  }
#pragma unroll
  for (int off=32; off>0; off>>=1){ s1+=__shfl_xor(s1,off); s2+=__shfl_xor(s2,off); }
  __shared__ double sh1[4], sh2[4];
  if (lane==0){ sh1[wid]=s1; sh2[wid]=s2; }
  __syncthreads();
  if (t==0){
    double a=sh1[0]+sh1[1]+sh1[2]+sh1[3], q=sh2[0]+sh2[1]+sh2[2]+sh2[3];
    double n=(double)(NB*NG);
    double mu=a/n, var=q/n - mu*mu;
    bn[c]=(float)mu;
    bn[COUT+c]=(float)(1.0/sqrt(var + 1e-5));
  }
}

// ---------------- final: BN affine + exact gelu, in-place on d_out ----------------
__global__ __launch_bounds__(256) void final_kernel(const float* __restrict__ bn, const float* __restrict__ gamma,
                                                    const float* __restrict__ beta, float* __restrict__ out){
  int i = blockIdx.x*256 + threadIdx.x;
  int c = (i >> 11) % COUT;
  float v = out[i];
  float y = (v - bn[c]) * bn[COUT + c];
  y = y*gamma[c] + beta[c];
  out[i] = y * 0.5f * (1.0f + erff(y * 0.70710678118654752f));
}

extern "C" void kernel_launch(void* const* d_in, const int* in_sizes, int n_in,
                              void* d_out, int out_size, void* d_ws, size_t ws_size,
                              hipStream_t stream){
  const float* xyz   = (const float*)d_in[0];
  const float* x     = (const float*)d_in[1];
  const float* gamma = (const float*)d_in[2];
  const float* beta  = (const float*)d_in[3];
  float* out = (float*)d_out;
  char* ws = (char*)d_ws;
  // workspace layout (all regions fully written before read every launch)
  int*    fps  = (int*)   (ws + 0);        //  32 KB
  int*    knn  = (int*)   (ws + 32768);    //   1 MB
  float*  xs   = (float*) (ws + 1081344);  // 128 KB
  float*  ys   = (float*) (ws + 1212416);
  float*  zs   = (float*) (ws + 1343488);
  float*  d2   = (float*) (ws + 1474560);
  double* parts= (double*)(ws + 1605632);  // 2048*8 doubles
  float*  scal = (float*) (ws + 1736704);  // 4 floats
  float*  bn   = (float*) (ws + 1736768);  // 384 floats

  setup_kernel   <<<dim3((NB*NPTS+255)/256), dim3(256), 0, stream>>>(xyz, xs, ys, zs, d2);
  fps_kernel     <<<dim3(NB),                dim3(1024),0, stream>>>(xyz, fps);
  knn_kernel     <<<dim3(NB*NG/4),           dim3(256), 0, stream>>>(xs, ys, zs, d2, fps, knn);
  stats_kernel   <<<dim3(NB*NG/4),           dim3(256), 0, stream>>>(x, xyz, fps, knn, parts);
  finalize_kernel<<<dim3(1),                 dim3(64),  0, stream>>>(parts, scal);
  main_kernel    <<<dim3(NB*NG/4),           dim3(256), 0, stream>>>(x, xyz, fps, knn, scal, out);
  bn_stats_kernel<<<dim3(COUT),              dim3(256), 0, stream>>>(out, bn);
  final_kernel   <<<dim3((NB*COUT*NG)/256),  dim3(256), 0, stream>>>(bn, gamma, beta, out);
}

// Round 4
// 2685.755 us; speedup vs baseline: 1.1692x; 1.1692x over previous
//
#include <hip/hip_runtime.h>
#include <cstdint>
#include <math.h>

#define NPTS 8192
#define NB 4
#define NG 2048
#define NK 32
#define CIN 96
#define COUT 192

typedef float v2f __attribute__((ext_vector_type(2)));

// ---------------- setup: SoA transpose + |p|^2 (bit-exact vs ref dst2) ----------------
__global__ __launch_bounds__(256) void setup_kernel(const float* __restrict__ xyz,
                                                    float* __restrict__ xs, float* __restrict__ ys,
                                                    float* __restrict__ zs, float* __restrict__ d2){
  int i = blockIdx.x*256 + threadIdx.x;
  if (i >= NB*NPTS) return;
  float x = xyz[3*i+0], y = xyz[3*i+1], z = xyz[3*i+2];
  xs[i]=x; ys[i]=y; zs[i]=z;
  d2[i] = __fadd_rn(__fadd_rn(__fmul_rn(x,x),__fmul_rn(y,y)),__fmul_rn(z,z));
}

// ---------------- FPS: 256 threads (1 wave/SIMD), 32 pts/lane, 2047 serial rounds ------
// Per round: packed update (16 v2f), pk-max tree + reverse == scan for local argmax,
// 6-step u64 wave reduce, lane0 LDS atomicMax into 4-slot rotating buffer, ONE barrier,
// broadcast slot read + winner coords from 128KB LDS float4 table.
__global__ __launch_bounds__(256,1) void fps_kernel(const float* __restrict__ xyz, int* __restrict__ fps_idx){
#pragma clang fp contract(off)   // selection-critical: no fma contraction anywhere here
  extern __shared__ char smem[];
  float4* ctab = (float4*)smem;                                    // NPTS * 16 B
  unsigned long long* slots = (unsigned long long*)(smem + NPTS*16); // 4 slots
  const int b = blockIdx.x;
  const int t = threadIdx.x;
  const float* base = xyz + (size_t)b*NPTS*3;
  // slot j holds flat points p0 = t+256*(2j) (.x) and p1 = t+256*(2j+1) (.y)
  v2f px[16], py[16], pz[16], D[16];
#pragma unroll
  for (int j=0;j<16;++j){
    int p0 = t + 512*j, p1 = p0 + 256;
    float x0=base[3*p0+0], y0=base[3*p0+1], z0=base[3*p0+2];
    float x1=base[3*p1+0], y1=base[3*p1+1], z1=base[3*p1+2];
    px[j]=(v2f){x0,x1}; py[j]=(v2f){y0,y1}; pz[j]=(v2f){z0,z1};
    D[j]=(v2f){1e10f,1e10f};                                        // ref init
    ctab[p0] = make_float4(x0,y0,z0,0.f);
    ctab[p1] = make_float4(x1,y1,z1,0.f);
  }
  if (t<4) slots[t]=0ULL;
  if (t==0) fps_idx[b*NG]=0;
  __syncthreads();
  float lx=base[0], ly=base[1], lz=base[2];   // seed = point 0
  for (int it=0; it<NG-1; ++it){
    // update D and running packed max
    v2f bm = (v2f){-1.0f,-1.0f};
#pragma unroll
    for (int j=0;j<16;++j){
      v2f dx = px[j]-lx, dy = py[j]-ly, dz = pz[j]-lz;
      v2f s = (dx*dx + dy*dy) + dz*dz;            // contract(off): IEEE rn mul/add
      v2f nd = __builtin_elementwise_min(D[j], s);
      D[j] = nd;
      bm = __builtin_elementwise_max(bm, nd);
    }
    float bd = fmaxf(bm.x, bm.y);
    // lowest local slot jj matching bd: reverse scan, last write wins
    int bj = 0;
#pragma unroll
    for (int j=15;j>=0;--j){
      if (D[j].y == bd) bj = 2*j+1;
      if (D[j].x == bd) bj = 2*j;
    }
    const int bp = t + (bj<<8);                   // flat point index
    // pack (dist_bits, ~idx): u64-max == np.argmax incl. lowest-index tie-break
    unsigned long long key = (((unsigned long long)__float_as_uint(bd))<<32)
                           | (unsigned long long)(unsigned)(~bp);
#pragma unroll
    for (int off=32; off>0; off>>=1){
      unsigned long long ok = __shfl_xor(key, off);
      if (ok > key) key = ok;
    }
    if ((t&63)==0) atomicMax(&slots[it&3], key);
    __syncthreads();                              // ONE barrier per round
    unsigned long long wk = slots[it&3];
    if (t==0) slots[(it+2)&3] = 0ULL;             // reset for round it+2 (barrier-separated)
    int pw = (int)(~(unsigned)wk);                // winner flat index
    float4 c = ctab[pw];                          // broadcast ds_read_b128
    lx=c.x; ly=c.y; lz=c.z;
    if (t==0) fps_idx[b*NG + it + 1] = pw;
  }
}

// ---------------- kNN: wave-wide exact top-32 (lexicographic (d,idx)) ----------------
__device__ __forceinline__ bool lexlt(float ad, int ai, float bd, int bi){
  return (ad < bd) || ((ad == bd) && (ai < bi));
}
__device__ __forceinline__ void sort_desc(float& d, int& i, int lane){
#pragma unroll
  for (int k=2;k<=64;k<<=1){
#pragma unroll
    for (int j=k>>1;j>0;j>>=1){
      float od = __shfl_xor(d, j);
      int   oi = __shfl_xor(i, j);
      bool dirUp = (lane & k) != 0;      // flipped -> overall descending
      bool lower = (lane & j) == 0;
      bool less  = lexlt(d,i,od,oi);
      bool keep  = (less == (lower == dirUp));
      if (!keep){ d=od; i=oi; }
    }
  }
}
__device__ __forceinline__ void merge_asc(float& d, int& i, int lane){
#pragma unroll
  for (int j=32;j>0;j>>=1){
    float od = __shfl_xor(d, j);
    int   oi = __shfl_xor(i, j);
    bool lower = (lane & j) == 0;
    bool less  = lexlt(d,i,od,oi);
    bool keep  = (less == lower);
    if (!keep){ d=od; i=oi; }
  }
}

__global__ __launch_bounds__(256) void knn_kernel(const float* __restrict__ xs, const float* __restrict__ ys,
                                                  const float* __restrict__ zs, const float* __restrict__ d2,
                                                  const int* __restrict__ fps_idx, int* __restrict__ knn_out){
  __shared__ float tx[256], ty[256], tz[256], td[256];
  const int tid = threadIdx.x;
  const int wid = tid>>6, lane = tid&63;
  const int pid = blockIdx.x*4 + wid;     // b*NG+g
  const int b = pid >> 11;
  const float* bx = xs + b*NPTS;
  const float* by = ys + b*NPTS;
  const float* bz = zs + b*NPTS;
  const float* bD = d2 + b*NPTS;
  const int fi = fps_idx[pid];
  const float ax = bx[fi], ay = by[fi], az = bz[fi];
  const float src2 = __fadd_rn(__fadd_rn(__fmul_rn(ax,ax),__fmul_rn(ay,ay)),__fmul_rn(az,az));
  float Ad = INFINITY; int Ai = 0x7fffffff;      // sorted-ascending top-64 (1/lane)
  float tau_d = INFINITY; int tau_i = 0x7fffffff; // current exact 32nd smallest
  for (int s=0; s<NPTS/256; ++s){
    __syncthreads();
    int gidx = s*256 + tid;
    tx[tid]=bx[gidx]; ty[tid]=by[gidx]; tz[tid]=bz[gidx]; td[tid]=bD[gidx];
    __syncthreads();
    float m0,m1,m2,m3; int i0,i1,i2,i3;
#define LOADJ(mj, ij, J) { int li = (J)*64 + lane; \
    float dot = __fadd_rn(__fadd_rn(__fmul_rn(ax,tx[li]),__fmul_rn(ay,ty[li])),__fmul_rn(az,tz[li])); \
    mj = __fadd_rn(__fadd_rn(__fmul_rn(-2.0f,dot), src2), td[li]); ij = s*256 + li; }
    LOADJ(m0,i0,0) LOADJ(m1,i1,1) LOADJ(m2,i2,2) LOADJ(m3,i3,3)
#undef LOADJ
    while (true){
      bool any = lexlt(m0,i0,tau_d,tau_i) || lexlt(m1,i1,tau_d,tau_i) ||
                 lexlt(m2,i2,tau_d,tau_i) || lexlt(m3,i3,tau_d,tau_i);
      if (__ballot(any) == 0ull) break;
      float cd = m0; int ci = i0; int sel = 0;
      if (lexlt(m1,i1,cd,ci)){ cd=m1; ci=i1; sel=1; }
      if (lexlt(m2,i2,cd,ci)){ cd=m2; ci=i2; sel=2; }
      if (lexlt(m3,i3,cd,ci)){ cd=m3; ci=i3; sel=3; }
      if      (sel==0) m0=INFINITY;
      else if (sel==1) m1=INFINITY;
      else if (sel==2) m2=INFINITY;
      else             m3=INFINITY;
      sort_desc(cd, ci, lane);                    // new chunk descending
      if (lexlt(cd,ci,Ad,Ai)){ Ad=cd; Ai=ci; }    // elementwise min -> bitonic
      merge_asc(Ad, Ai, lane);                    // re-sort ascending
      tau_d = __shfl(Ad, 31);
      tau_i = __shfl(Ai, 31);
    }
  }
  if (lane < NK) knn_out[pid*NK + lane] = Ai;
}

// ---------------- global stats (fp64 partials per block) ----------------
__global__ __launch_bounds__(256) void stats_kernel(const float* __restrict__ x, const float* __restrict__ xyz,
                                                    const int* __restrict__ fps_idx, const int* __restrict__ knn,
                                                    double* __restrict__ partials){
  const int tid=threadIdx.x, wid=tid>>6, lane=tid&63;
  const int pid = blockIdx.x*4 + wid;
  const int b = pid>>11;
  const int fi = fps_idx[pid];
  const float* xb = x + (size_t)b*NPTS*CIN;
  const float* zb = xyz + (size_t)b*NPTS*3;
  const float lc0 = xb[fi*CIN + lane];
  float lc1 = 0.f; if (lane<32) lc1 = xb[fi*CIN + 64 + lane];
  float czv = 0.f; if (lane<3)  czv = zb[fi*3 + lane];
  double s1=0.0, s2=0.0, a1=0.0, a2=0.0;
  for (int k=0;k<NK;++k){
    int idx = knn[pid*NK + k];
    float d0 = __fsub_rn(xb[idx*CIN + lane], lc0);
    s1 += (double)d0; s2 += (double)d0*(double)d0;
    if (lane<32){
      float d1 = __fsub_rn(xb[idx*CIN + 64 + lane], lc1);
      s1 += (double)d1; s2 += (double)d1*(double)d1;
    }
    if (lane<3){
      float w = __fsub_rn(zb[idx*3 + lane], czv);
      a1 += (double)w; a2 += (double)w*(double)w;
    }
  }
#pragma unroll
  for (int off=32; off>0; off>>=1){ s1 += __shfl_xor(s1,off); s2 += __shfl_xor(s2,off); }
  __shared__ double shx[4][2];
  __shared__ double shz[4][3][2];
  if (lane==0){ shx[wid][0]=s1; shx[wid][1]=s2; }
  if (lane<3){ shz[wid][lane][0]=a1; shz[wid][lane][1]=a2; }
  __syncthreads();
  if (tid==0){
    double u0=0,u1=0;
    for (int w=0;w<4;++w){ u0+=shx[w][0]; u1+=shx[w][1]; }
    double* outp = partials + (size_t)blockIdx.x*8;
    outp[0]=u0; outp[1]=u1;
    for (int axq=0; axq<3; ++axq){
      double v0=0,v1=0;
      for (int w=0;w<4;++w){ v0+=shz[w][axq][0]; v1+=shz[w][axq][1]; }
      outp[2+2*axq]=v0; outp[3+2*axq]=v1;
    }
  }
}

__global__ void finalize_kernel(const double* __restrict__ partials, float* __restrict__ scal){
  const int lane = threadIdx.x;  // 64 threads, 1 wave
  double s1=0,s2=0;
  double z0a=0,z0b=0,z1a=0,z1b=0,z2a=0,z2b=0;
  for (int i=0;i<32;++i){
    const double* p = partials + (size_t)(lane*32+i)*8;   // 32 consecutive blocks -> same b
    s1+=p[0]; s2+=p[1];
    z0a+=p[2]; z0b+=p[3]; z1a+=p[4]; z1b+=p[5]; z2a+=p[6]; z2b+=p[7];
  }
#pragma unroll
  for (int off=32; off>0; off>>=1){ s1+=__shfl_xor(s1,off); s2+=__shfl_xor(s2,off); }
#pragma unroll
  for (int off=8; off>0; off>>=1){
    z0a+=__shfl_xor(z0a,off); z0b+=__shfl_xor(z0b,off);
    z1a+=__shfl_xor(z1a,off); z1b+=__shfl_xor(z1b,off);
    z2a+=__shfl_xor(z2a,off); z2b+=__shfl_xor(z2b,off);
  }
  __shared__ double zb[4][3][2];
  if ((lane&15)==0){
    int b = lane>>4;
    zb[b][0][0]=z0a; zb[b][0][1]=z0b;
    zb[b][1][0]=z1a; zb[b][1][1]=z1b;
    zb[b][2][0]=z2a; zb[b][2][1]=z2b;
  }
  __syncthreads();
  if (lane==0){
    double nx = (double)NB*NG*NK*CIN;
    double varx = (s2 - s1*s1/nx)/(nx-1.0);
    float stdx = (float)sqrt(varx);
    double t1=0,t2=0;
    for (int b=0;b<4;++b) for (int a=0;a<3;++a){ t1+=zb[b][a][0]; t2+=zb[b][a][1]; }
    double nz = (double)NB*NG*NK*3;
    double varz = (t2 - t1*t1/nz)/(nz-1.0);
    float stdz = (float)sqrt(varz);
    float sdiv = stdz + 1e-5f;
    double n2 = (double)NG*NK;
    double acc=0.0;
    for (int b=0;b<4;++b) for (int a=0;a<3;++a){
      double v = (zb[b][a][1] - zb[b][a][0]*zb[b][a][0]/n2)/(n2-1.0);
      acc += sqrt(v);
    }
    float gstd = (float)(acc/12.0) / sdiv;   // std(x4) = std(raw)/(std_xyz+1e-5)
    float sig = 0.26f*(1.0f+gstd) + 1e-6f;
    float blend = 1.0f/(1.0f + expf(-(gstd-0.1f)*10.0f));
    scal[0] = 1.0f/(stdx + 1e-5f);
    scal[1] = 1.0f/sdiv;
    scal[2] = 1.0f/sig;
    scal[3] = blend;
  }
}

// ---------------- main fused kernel: pe + weighting + max/mean over K -> lc in d_out ----------------
__global__ __launch_bounds__(256) void main_kernel(const float* __restrict__ x, const float* __restrict__ xyz,
                                                   const int* __restrict__ fps_idx, const int* __restrict__ knn,
                                                   const float* __restrict__ scal, float* __restrict__ lc_out){
  const int tid=threadIdx.x, wid=tid>>6, lane=tid&63;
  const int pid = blockIdx.x*4 + wid;
  const int b = pid>>11, g = pid&2047;
  const float inv_x = scal[0], inv_z = scal[1], inv_sig = scal[2], blend = scal[3];
  const float omb = 1.0f - blend;
  const int fi = fps_idx[pid];
  const float* xb = x + (size_t)b*NPTS*CIN;
  const float* zb = xyz + (size_t)b*NPTS*3;
  const float cx = zb[fi*3+0], cy = zb[fi*3+1], cz = zb[fi*3+2];
  // lane's 3 channels: c = lane, 64+lane, 128+lane
  const float lcx0 = xb[fi*CIN + lane];
  const float lcx1 = (lane<32) ? xb[fi*CIN + 64 + lane] : xb[fi*CIN + lane - 32];
  const float lcx2 = xb[fi*CIN + 32 + lane];
  // r0: fourier, dim = lane>>5 (0/1), rr = lane&31, freq = rr>>1, odd->cos
  const int dim0 = lane>>5;
  const int rr0 = lane&31;
  const bool cos0 = rr0 & 1;
  const float bs0 = 100.0f / powf(1000.0f, (float)(rr0>>1) * (1.0f/16.0f));
  // r1: lane<32 fourier dim=2; lane>=32 adaptive dim=0, j=lane-32
  const bool cos1 = lane & 1;
  const float bs1 = 100.0f / powf(1000.0f, (float)((lane&31)>>1) * (1.0f/16.0f));
  const float fv1 = (float)(-1.0 + 2.0*(double)(lane-32+1)/33.0);
  // r2: adaptive, cc=32+lane: dim=cc>>5 (1/2), j=cc&31
  const int dim2 = (32+lane)>>5;
  const int j2 = (32+lane)&31;
  const float fv2 = (float)(-1.0 + 2.0*(double)(j2+1)/33.0);

  float mx0=-INFINITY, mx1=-INFINITY, mx2=-INFINITY;
  float sm0=0.f, sm1=0.f, sm2=0.f;
  for (int k=0;k<NK;++k){
    const int idx = knn[pid*NK + k];
    const float p0 = zb[idx*3+0], p1 = zb[idx*3+1], p2v = zb[idx*3+2];
    const float xn0 = (p0-cx)*inv_z, xn1 = (p1-cy)*inv_z, xn2 = (p2v-cz)*inv_z;
    const float xk0 = xb[idx*CIN + lane];
    float xk1 = 0.f; if (lane<32) xk1 = xb[idx*CIN + 64 + lane];
    { // r0
      float v = dim0 ? xn1 : xn0;
      float a = v * bs0;
      float pe = cos0 ? __cosf(a) : __sinf(a);
      float f = (xk0 - lcx0) * inv_x;
      float w = (f + pe) * pe;
      mx0 = fmaxf(mx0, w); sm0 += w;
    }
    { // r1
      float pe, f;
      if (lane < 32){
        float a = xn2 * bs1;
        pe = cos1 ? __cosf(a) : __sinf(a);
        f = (xk1 - lcx1) * inv_x;
      } else {
        float zq = (xn0 - fv1) * inv_sig;
        pe = blend * __expf(-0.5f*zq*zq) + omb * __cosf(zq);
        f = lcx1;   // raw center features (second concat half)
      }
      float w = (f + pe) * pe;
      mx1 = fmaxf(mx1, w); sm1 += w;
    }
    { // r2
      float v = (dim2==1) ? xn1 : xn2;
      float zq = (v - fv2) * inv_sig;
      float pe = blend * __expf(-0.5f*zq*zq) + omb * __cosf(zq);
      float w = (lcx2 + pe) * pe;
      mx2 = fmaxf(mx2, w); sm2 += w;
    }
  }
  const size_t obase = ((size_t)b*COUT)*NG + g;
  lc_out[obase + (size_t)lane*NG]       = mx0 + sm0*(1.0f/32.0f);
  lc_out[obase + (size_t)(64+lane)*NG]  = mx1 + sm1*(1.0f/32.0f);
  lc_out[obase + (size_t)(128+lane)*NG] = mx2 + sm2*(1.0f/32.0f);
}

// ---------------- batch-norm stats (per channel over B,G; ddof=0) ----------------
__global__ __launch_bounds__(256) void bn_stats_kernel(const float* __restrict__ lc, float* __restrict__ bn){
  const int c = blockIdx.x, t = threadIdx.x, lane=t&63, wid=t>>6;
  double s1=0.0, s2=0.0;
  for (int i=t; i<NB*NG; i+=256){
    int b=i>>11, g=i&2047;
    float v = lc[((size_t)(b*COUT)+c)*NG + g];
    s1 += (double)v; s2 += (double)v*(double)v;
  }
#pragma unroll
  for (int off=32; off>0; off>>=1){ s1+=__shfl_xor(s1,off); s2+=__shfl_xor(s2,off); }
  __shared__ double sh1[4], sh2[4];
  if (lane==0){ sh1[wid]=s1; sh2[wid]=s2; }
  __syncthreads();
  if (t==0){
    double a=sh1[0]+sh1[1]+sh1[2]+sh1[3], q=sh2[0]+sh2[1]+sh2[2]+sh2[3];
    double n=(double)(NB*NG);
    double mu=a/n, var=q/n - mu*mu;
    bn[c]=(float)mu;
    bn[COUT+c]=(float)(1.0/sqrt(var + 1e-5));
  }
}

// ---------------- final: BN affine + exact gelu, in-place on d_out ----------------
__global__ __launch_bounds__(256) void final_kernel(const float* __restrict__ bn, const float* __restrict__ gamma,
                                                    const float* __restrict__ beta, float* __restrict__ out){
  int i = blockIdx.x*256 + threadIdx.x;
  int c = (i >> 11) % COUT;
  float v = out[i];
  float y = (v - bn[c]) * bn[COUT + c];
  y = y*gamma[c] + beta[c];
  out[i] = y * 0.5f * (1.0f + erff(y * 0.70710678118654752f));
}

extern "C" void kernel_launch(void* const* d_in, const int* in_sizes, int n_in,
                              void* d_out, int out_size, void* d_ws, size_t ws_size,
                              hipStream_t stream){
  const float* xyz   = (const float*)d_in[0];
  const float* x     = (const float*)d_in[1];
  const float* gamma = (const float*)d_in[2];
  const float* beta  = (const float*)d_in[3];
  float* out = (float*)d_out;
  char* ws = (char*)d_ws;
  // workspace layout (all regions fully written before read every launch)
  int*    fps  = (int*)   (ws + 0);        //  32 KB
  int*    knn  = (int*)   (ws + 32768);    //   1 MB
  float*  xs   = (float*) (ws + 1081344);  // 128 KB
  float*  ys   = (float*) (ws + 1212416);
  float*  zs   = (float*) (ws + 1343488);
  float*  d2   = (float*) (ws + 1474560);
  double* parts= (double*)(ws + 1605632);  // 2048*8 doubles
  float*  scal = (float*) (ws + 1736704);  // 4 floats
  float*  bn   = (float*) (ws + 1736768);  // 384 floats

  const int fps_lds = NPTS*16 + 4*8;       // 128KB coords table + 4 u64 slots
  static bool attr_set = false;
  (void)hipFuncSetAttribute(reinterpret_cast<const void*>(fps_kernel),
                            hipFuncAttributeMaxDynamicSharedMemorySize, fps_lds);

  setup_kernel   <<<dim3((NB*NPTS+255)/256), dim3(256), 0, stream>>>(xyz, xs, ys, zs, d2);
  fps_kernel     <<<dim3(NB),                dim3(256), fps_lds, stream>>>(xyz, fps);
  knn_kernel     <<<dim3(NB*NG/4),           dim3(256), 0, stream>>>(xs, ys, zs, d2, fps, knn);
  stats_kernel   <<<dim3(NB*NG/4),           dim3(256), 0, stream>>>(x, xyz, fps, knn, parts);
  finalize_kernel<<<dim3(1),                 dim3(64),  0, stream>>>(parts, scal);
  main_kernel    <<<dim3(NB*NG/4),           dim3(256), 0, stream>>>(x, xyz, fps, knn, scal, out);
  bn_stats_kernel<<<dim3(COUT),              dim3(256), 0, stream>>>(out, bn);
  final_kernel   <<<dim3((NB*COUT*NG)/256),  dim3(256), 0, stream>>>(bn, gamma, beta, out);
}

// Round 5
// 2554.807 us; speedup vs baseline: 1.2291x; 1.0513x over previous
//
#include <hip/hip_runtime.h>
#include <cstdint>
#include <math.h>

#define NPTS 8192
#define NB 4
#define NG 2048
#define NK 32
#define CIN 96
#define COUT 192

typedef float v2f __attribute__((ext_vector_type(2)));
typedef unsigned long long ull;

// ---------------- setup: SoA transpose + |p|^2 (bit-exact vs ref dst2) ----------------
__global__ __launch_bounds__(256) void setup_kernel(const float* __restrict__ xyz,
                                                    float* __restrict__ xs, float* __restrict__ ys,
                                                    float* __restrict__ zs, float* __restrict__ d2){
  int i = blockIdx.x*256 + threadIdx.x;
  if (i >= NB*NPTS) return;
  float x = xyz[3*i+0], y = xyz[3*i+1], z = xyz[3*i+2];
  xs[i]=x; ys[i]=y; zs[i]=z;
  d2[i] = __fadd_rn(__fadd_rn(__fmul_rn(x,x),__fmul_rn(y,y)),__fmul_rn(z,z));
}

// DPP wave reductions (VALU pipe, no LDS): row_shr 1/2/4/8 + bcast15 + bcast31 -> lane63
template<int CTRL>
__device__ __forceinline__ float dppmaxf(float v){
  int o = __builtin_amdgcn_update_dpp(__float_as_int(v), __float_as_int(v), CTRL, 0xf, 0xf, false);
  return fmaxf(v, __int_as_float(o));
}
template<int CTRL>
__device__ __forceinline__ unsigned dppminu(unsigned v){
  unsigned o = (unsigned)__builtin_amdgcn_update_dpp((int)v, (int)v, CTRL, 0xf, 0xf, false);
  return (o < v) ? o : v;
}
__device__ __forceinline__ float wavemaxf(float v){   // result valid in lane 63
  v = dppmaxf<0x111>(v); v = dppmaxf<0x112>(v); v = dppmaxf<0x114>(v);
  v = dppmaxf<0x118>(v); v = dppmaxf<0x142>(v); v = dppmaxf<0x143>(v);
  return v;
}
__device__ __forceinline__ unsigned waveminu(unsigned v){  // result valid in lane 63
  v = dppminu<0x111>(v); v = dppminu<0x112>(v); v = dppminu<0x114>(v);
  v = dppminu<0x118>(v); v = dppminu<0x142>(v); v = dppminu<0x143>(v);
  return v;
}

// ---------------- FPS: 512 threads (2 waves/SIMD), 16 pts/lane, 2047 serial rounds ----
// Per round: packed update (8 v2f), DPP f32 wave-max, matching lanes scan lowest idx,
// DPP u32 wave-min, lane63 writes packed u64 key to double-buffered LDS slot, ONE
// barrier, all waves reduce 8 keys, winner coords from 128KB LDS float4 table.
__global__ __launch_bounds__(512,2) void fps_kernel(const float* __restrict__ xyz, int* __restrict__ fps_idx){
#pragma clang fp contract(off)   // selection-critical: no fma contraction anywhere here
  extern __shared__ char smem[];
  float4* ctab = (float4*)smem;                                  // NPTS * 16 B
  ull* wavekeys = (ull*)(smem + NPTS*16);                        // [2][8]
  const int b = blockIdx.x;
  const int t = threadIdx.x;
  const int w = t>>6, lane = t&63;
  const float* base = xyz + (size_t)b*NPTS*3;
  // slot j holds flat points p0 = t+1024j (.x) and p1 = p0+512 (.y)
  v2f px[8], py[8], pz[8], D[8];
#pragma unroll
  for (int j=0;j<8;++j){
    int p0 = t + 1024*j, p1 = p0 + 512;
    float x0=base[3*p0+0], y0=base[3*p0+1], z0=base[3*p0+2];
    float x1=base[3*p1+0], y1=base[3*p1+1], z1=base[3*p1+2];
    px[j]=(v2f){x0,x1}; py[j]=(v2f){y0,y1}; pz[j]=(v2f){z0,z1};
    D[j]=(v2f){1e10f,1e10f};                                     // ref init
    ctab[p0] = make_float4(x0,y0,z0,0.f);
    ctab[p1] = make_float4(x1,y1,z1,0.f);
  }
  if (t==0) fps_idx[b*NG]=0;
  __syncthreads();
  float lx=base[0], ly=base[1], lz=base[2];   // seed = point 0
  for (int it=0; it<NG-1; ++it){
    // update D, track packed running max
    v2f bm = (v2f){-1.0f,-1.0f};
#pragma unroll
    for (int j=0;j<8;++j){
      v2f dx = px[j]-lx, dy = py[j]-ly, dz = pz[j]-lz;
      v2f s = (dx*dx + dy*dy) + dz*dz;            // contract(off): IEEE rn mul/add
      v2f nd = __builtin_elementwise_min(D[j], s);
      D[j] = nd;
      bm = __builtin_elementwise_max(bm, nd);
    }
    float bd = fmaxf(bm.x, bm.y);                 // lane max
    float m = wavemaxf(bd);                       // lane63 = wave max
    float bdw = __int_as_float(__builtin_amdgcn_readlane(__float_as_int(m), 63));
    // lanes achieving the wave max: lowest local original index
    unsigned li = 0xFFFFFFFFu;
    if (bd == bdw){
#pragma unroll
      for (int j=7;j>=0;--j){                     // descending: last write = lowest idx
        if (D[j].y == bdw) li = (unsigned)(t + (j<<10) + 512);
        if (D[j].x == bdw) li = (unsigned)(t + (j<<10));
      }
    }
    unsigned mn = waveminu(li);                   // lane63 = wave min idx among matches
    if (lane==63)
      wavekeys[(it&1)*8 + w] = (((ull)__float_as_uint(bdw))<<32) | (ull)(~mn);
    __syncthreads();                              // ONE barrier per round
    // all waves redundantly reduce the 8 wave keys (broadcast LDS reads)
    const ull* wk = wavekeys + (it&1)*8;
    ull k = wk[0];
#pragma unroll
    for (int q=1;q<8;++q){ ull o = wk[q]; if (o > k) k = o; }    // max key = argmax w/ lowest idx
    unsigned pw = ~(unsigned)k;                   // winner flat index
    float4 c = ctab[pw];                          // broadcast ds_read_b128
    lx=c.x; ly=c.y; lz=c.z;
    if (t==0) fps_idx[b*NG + it + 1] = (int)pw;
  }
}

// ---------------- kNN: wave-wide exact top-32 (lexicographic (d,idx)) ----------------
__device__ __forceinline__ bool lexlt(float ad, int ai, float bd, int bi){
  return (ad < bd) || ((ad == bd) && (ai < bi));
}
__device__ __forceinline__ void sort_desc(float& d, int& i, int lane){
#pragma unroll
  for (int k=2;k<=64;k<<=1){
#pragma unroll
    for (int j=k>>1;j>0;j>>=1){
      float od = __shfl_xor(d, j);
      int   oi = __shfl_xor(i, j);
      bool dirUp = (lane & k) != 0;      // flipped -> overall descending
      bool lower = (lane & j) == 0;
      bool less  = lexlt(d,i,od,oi);
      bool keep  = (less == (lower == dirUp));
      if (!keep){ d=od; i=oi; }
    }
  }
}
__device__ __forceinline__ void merge_asc(float& d, int& i, int lane){
#pragma unroll
  for (int j=32;j>0;j>>=1){
    float od = __shfl_xor(d, j);
    int   oi = __shfl_xor(i, j);
    bool lower = (lane & j) == 0;
    bool less  = lexlt(d,i,od,oi);
    bool keep  = (less == lower);
    if (!keep){ d=od; i=oi; }
  }
}

__global__ __launch_bounds__(256) void knn_kernel(const float* __restrict__ xs, const float* __restrict__ ys,
                                                  const float* __restrict__ zs, const float* __restrict__ d2,
                                                  const int* __restrict__ fps_idx, int* __restrict__ knn_out){
  __shared__ float tx[256], ty[256], tz[256], td[256];
  const int tid = threadIdx.x;
  const int wid = tid>>6, lane = tid&63;
  const int pid = blockIdx.x*4 + wid;     // b*NG+g
  const int b = pid >> 11;
  const float* bx = xs + b*NPTS;
  const float* by = ys + b*NPTS;
  const float* bz = zs + b*NPTS;
  const float* bD = d2 + b*NPTS;
  const int fi = fps_idx[pid];
  const float ax = bx[fi], ay = by[fi], az = bz[fi];
  const float src2 = __fadd_rn(__fadd_rn(__fmul_rn(ax,ax),__fmul_rn(ay,ay)),__fmul_rn(az,az));
  float Ad = INFINITY; int Ai = 0x7fffffff;      // sorted-ascending top-64 (1/lane)
  float tau_d = INFINITY; int tau_i = 0x7fffffff; // current exact 32nd smallest
  for (int s=0; s<NPTS/256; ++s){
    __syncthreads();
    int gidx = s*256 + tid;
    tx[tid]=bx[gidx]; ty[tid]=by[gidx]; tz[tid]=bz[gidx]; td[tid]=bD[gidx];
    __syncthreads();
    float m0,m1,m2,m3; int i0,i1,i2,i3;
#define LOADJ(mj, ij, J) { int li = (J)*64 + lane; \
    float dot = __fadd_rn(__fadd_rn(__fmul_rn(ax,tx[li]),__fmul_rn(ay,ty[li])),__fmul_rn(az,tz[li])); \
    mj = __fadd_rn(__fadd_rn(__fmul_rn(-2.0f,dot), src2), td[li]); ij = s*256 + li; }
    LOADJ(m0,i0,0) LOADJ(m1,i1,1) LOADJ(m2,i2,2) LOADJ(m3,i3,3)
#undef LOADJ
    while (true){
      bool any = lexlt(m0,i0,tau_d,tau_i) || lexlt(m1,i1,tau_d,tau_i) ||
                 lexlt(m2,i2,tau_d,tau_i) || lexlt(m3,i3,tau_d,tau_i);
      if (__ballot(any) == 0ull) break;
      float cd = m0; int ci = i0; int sel = 0;
      if (lexlt(m1,i1,cd,ci)){ cd=m1; ci=i1; sel=1; }
      if (lexlt(m2,i2,cd,ci)){ cd=m2; ci=i2; sel=2; }
      if (lexlt(m3,i3,cd,ci)){ cd=m3; ci=i3; sel=3; }
      if      (sel==0) m0=INFINITY;
      else if (sel==1) m1=INFINITY;
      else if (sel==2) m2=INFINITY;
      else             m3=INFINITY;
      sort_desc(cd, ci, lane);                    // new chunk descending
      if (lexlt(cd,ci,Ad,Ai)){ Ad=cd; Ai=ci; }    // elementwise min -> bitonic
      merge_asc(Ad, Ai, lane);                    // re-sort ascending
      tau_d = __shfl(Ad, 31);
      tau_i = __shfl(Ai, 31);
    }
  }
  if (lane < NK) knn_out[pid*NK + lane] = Ai;
}

// ---------------- global stats (fp64 partials per block) ----------------
__global__ __launch_bounds__(256) void stats_kernel(const float* __restrict__ x, const float* __restrict__ xyz,
                                                    const int* __restrict__ fps_idx, const int* __restrict__ knn,
                                                    double* __restrict__ partials){
  const int tid=threadIdx.x, wid=tid>>6, lane=tid&63;
  const int pid = blockIdx.x*4 + wid;
  const int b = pid>>11;
  const int fi = fps_idx[pid];
  const float* xb = x + (size_t)b*NPTS*CIN;
  const float* zb = xyz + (size_t)b*NPTS*3;
  const float lc0 = xb[fi*CIN + lane];
  float lc1 = 0.f; if (lane<32) lc1 = xb[fi*CIN + 64 + lane];
  float czv = 0.f; if (lane<3)  czv = zb[fi*3 + lane];
  double s1=0.0, s2=0.0, a1=0.0, a2=0.0;
  for (int k=0;k<NK;++k){
    int idx = knn[pid*NK + k];
    float d0 = __fsub_rn(xb[idx*CIN + lane], lc0);
    s1 += (double)d0; s2 += (double)d0*(double)d0;
    if (lane<32){
      float d1 = __fsub_rn(xb[idx*CIN + 64 + lane], lc1);
      s1 += (double)d1; s2 += (double)d1*(double)d1;
    }
    if (lane<3){
      float w = __fsub_rn(zb[idx*3 + lane], czv);
      a1 += (double)w; a2 += (double)w*(double)w;
    }
  }
#pragma unroll
  for (int off=32; off>0; off>>=1){ s1 += __shfl_xor(s1,off); s2 += __shfl_xor(s2,off); }
  __shared__ double shx[4][2];
  __shared__ double shz[4][3][2];
  if (lane==0){ shx[wid][0]=s1; shx[wid][1]=s2; }
  if (lane<3){ shz[wid][lane][0]=a1; shz[wid][lane][1]=a2; }
  __syncthreads();
  if (tid==0){
    double u0=0,u1=0;
    for (int w=0;w<4;++w){ u0+=shx[w][0]; u1+=shx[w][1]; }
    double* outp = partials + (size_t)blockIdx.x*8;
    outp[0]=u0; outp[1]=u1;
    for (int axq=0; axq<3; ++axq){
      double v0=0,v1=0;
      for (int w=0;w<4;++w){ v0+=shz[w][axq][0]; v1+=shz[w][axq][1]; }
      outp[2+2*axq]=v0; outp[3+2*axq]=v1;
    }
  }
}

__global__ void finalize_kernel(const double* __restrict__ partials, float* __restrict__ scal){
  const int lane = threadIdx.x;  // 64 threads, 1 wave
  double s1=0,s2=0;
  double z0a=0,z0b=0,z1a=0,z1b=0,z2a=0,z2b=0;
  for (int i=0;i<32;++i){
    const double* p = partials + (size_t)(lane*32+i)*8;   // 32 consecutive blocks -> same b
    s1+=p[0]; s2+=p[1];
    z0a+=p[2]; z0b+=p[3]; z1a+=p[4]; z1b+=p[5]; z2a+=p[6]; z2b+=p[7];
  }
#pragma unroll
  for (int off=32; off>0; off>>=1){ s1+=__shfl_xor(s1,off); s2+=__shfl_xor(s2,off); }
#pragma unroll
  for (int off=8; off>0; off>>=1){
    z0a+=__shfl_xor(z0a,off); z0b+=__shfl_xor(z0b,off);
    z1a+=__shfl_xor(z1a,off); z1b+=__shfl_xor(z1b,off);
    z2a+=__shfl_xor(z2a,off); z2b+=__shfl_xor(z2b,off);
  }
  __shared__ double zb[4][3][2];
  if ((lane&15)==0){
    int b = lane>>4;
    zb[b][0][0]=z0a; zb[b][0][1]=z0b;
    zb[b][1][0]=z1a; zb[b][1][1]=z1b;
    zb[b][2][0]=z2a; zb[b][2][1]=z2b;
  }
  __syncthreads();
  if (lane==0){
    double nx = (double)NB*NG*NK*CIN;
    double varx = (s2 - s1*s1/nx)/(nx-1.0);
    float stdx = (float)sqrt(varx);
    double t1=0,t2=0;
    for (int b=0;b<4;++b) for (int a=0;a<3;++a){ t1+=zb[b][a][0]; t2+=zb[b][a][1]; }
    double nz = (double)NB*NG*NK*3;
    double varz = (t2 - t1*t1/nz)/(nz-1.0);
    float stdz = (float)sqrt(varz);
    float sdiv = stdz + 1e-5f;
    double n2 = (double)NG*NK;
    double acc=0.0;
    for (int b=0;b<4;++b) for (int a=0;a<3;++a){
      double v = (zb[b][a][1] - zb[b][a][0]*zb[b][a][0]/n2)/(n2-1.0);
      acc += sqrt(v);
    }
    float gstd = (float)(acc/12.0) / sdiv;   // std(x4) = std(raw)/(std_xyz+1e-5)
    float sig = 0.26f*(1.0f+gstd) + 1e-6f;
    float blend = 1.0f/(1.0f + expf(-(gstd-0.1f)*10.0f));
    scal[0] = 1.0f/(stdx + 1e-5f);
    scal[1] = 1.0f/sdiv;
    scal[2] = 1.0f/sig;
    scal[3] = blend;
  }
}

// ---------------- main fused kernel: pe + weighting + max/mean over K -> lc in d_out ----------------
__global__ __launch_bounds__(256) void main_kernel(const float* __restrict__ x, const float* __restrict__ xyz,
                                                   const int* __restrict__ fps_idx, const int* __restrict__ knn,
                                                   const float* __restrict__ scal, float* __restrict__ lc_out){
  const int tid=threadIdx.x, wid=tid>>6, lane=tid&63;
  const int pid = blockIdx.x*4 + wid;
  const int b = pid>>11, g = pid&2047;
  const float inv_x = scal[0], inv_z = scal[1], inv_sig = scal[2], blend = scal[3];
  const float omb = 1.0f - blend;
  const int fi = fps_idx[pid];
  const float* xb = x + (size_t)b*NPTS*CIN;
  const float* zb = xyz + (size_t)b*NPTS*3;
  const float cx = zb[fi*3+0], cy = zb[fi*3+1], cz = zb[fi*3+2];
  // lane's 3 channels: c = lane, 64+lane, 128+lane
  const float lcx0 = xb[fi*CIN + lane];
  const float lcx1 = (lane<32) ? xb[fi*CIN + 64 + lane] : xb[fi*CIN + lane - 32];
  const float lcx2 = xb[fi*CIN + 32 + lane];
  // r0: fourier, dim = lane>>5 (0/1), rr = lane&31, freq = rr>>1, odd->cos
  const int dim0 = lane>>5;
  const int rr0 = lane&31;
  const bool cos0 = rr0 & 1;
  const float bs0 = 100.0f / powf(1000.0f, (float)(rr0>>1) * (1.0f/16.0f));
  // r1: lane<32 fourier dim=2; lane>=32 adaptive dim=0, j=lane-32
  const bool cos1 = lane & 1;
  const float bs1 = 100.0f / powf(1000.0f, (float)((lane&31)>>1) * (1.0f/16.0f));
  const float fv1 = (float)(-1.0 + 2.0*(double)(lane-32+1)/33.0);
  // r2: adaptive, cc=32+lane: dim=cc>>5 (1/2), j=cc&31
  const int dim2 = (32+lane)>>5;
  const int j2 = (32+lane)&31;
  const float fv2 = (float)(-1.0 + 2.0*(double)(j2+1)/33.0);

  float mx0=-INFINITY, mx1=-INFINITY, mx2=-INFINITY;
  float sm0=0.f, sm1=0.f, sm2=0.f;
  for (int k=0;k<NK;++k){
    const int idx = knn[pid*NK + k];
    const float p0 = zb[idx*3+0], p1 = zb[idx*3+1], p2v = zb[idx*3+2];
    const float xn0 = (p0-cx)*inv_z, xn1 = (p1-cy)*inv_z, xn2 = (p2v-cz)*inv_z;
    const float xk0 = xb[idx*CIN + lane];
    float xk1 = 0.f; if (lane<32) xk1 = xb[idx*CIN + 64 + lane];
    { // r0
      float v = dim0 ? xn1 : xn0;
      float a = v * bs0;
      float pe = cos0 ? __cosf(a) : __sinf(a);
      float f = (xk0 - lcx0) * inv_x;
      float w = (f + pe) * pe;
      mx0 = fmaxf(mx0, w); sm0 += w;
    }
    { // r1
      float pe, f;
      if (lane < 32){
        float a = xn2 * bs1;
        pe = cos1 ? __cosf(a) : __sinf(a);
        f = (xk1 - lcx1) * inv_x;
      } else {
        float zq = (xn0 - fv1) * inv_sig;
        pe = blend * __expf(-0.5f*zq*zq) + omb * __cosf(zq);
        f = lcx1;   // raw center features (second concat half)
      }
      float w = (f + pe) * pe;
      mx1 = fmaxf(mx1, w); sm1 += w;
    }
    { // r2
      float v = (dim2==1) ? xn1 : xn2;
      float zq = (v - fv2) * inv_sig;
      float pe = blend * __expf(-0.5f*zq*zq) + omb * __cosf(zq);
      float w = (lcx2 + pe) * pe;
      mx2 = fmaxf(mx2, w); sm2 += w;
    }
  }
  const size_t obase = ((size_t)b*COUT)*NG + g;
  lc_out[obase + (size_t)lane*NG]       = mx0 + sm0*(1.0f/32.0f);
  lc_out[obase + (size_t)(64+lane)*NG]  = mx1 + sm1*(1.0f/32.0f);
  lc_out[obase + (size_t)(128+lane)*NG] = mx2 + sm2*(1.0f/32.0f);
}

// ---------------- batch-norm stats (per channel over B,G; ddof=0) ----------------
__global__ __launch_bounds__(256) void bn_stats_kernel(const float* __restrict__ lc, float* __restrict__ bn){
  const int c = blockIdx.x, t = threadIdx.x, lane=t&63, wid=t>>6;
  double s1=0.0, s2=0.0;
  for (int i=t; i<NB*NG; i+=256){
    int b=i>>11, g=i&2047;
    float v = lc[((size_t)(b*COUT)+c)*NG + g];
    s1 += (double)v; s2 += (double)v*(double)v;
  }
#pragma unroll
  for (int off=32; off>0; off>>=1){ s1+=__shfl_xor(s1,off); s2+=__shfl_xor(s2,off); }
  __shared__ double sh1[4], sh2[4];
  if (lane==0){ sh1[wid]=s1; sh2[wid]=s2; }
  __syncthreads();
  if (t==0){
    double a=sh1[0]+sh1[1]+sh1[2]+sh1[3], q=sh2[0]+sh2[1]+sh2[2]+sh2[3];
    double n=(double)(NB*NG);
    double mu=a/n, var=q/n - mu*mu;
    bn[c]=(float)mu;
    bn[COUT+c]=(float)(1.0/sqrt(var + 1e-5));
  }
}

// ---------------- final: BN affine + exact gelu, in-place on d_out ----------------
__global__ __launch_bounds__(256) void final_kernel(const float* __restrict__ bn, const float* __restrict__ gamma,
                                                    const float* __restrict__ beta, float* __restrict__ out){
  int i = blockIdx.x*256 + threadIdx.x;
  int c = (i >> 11) % COUT;
  float v = out[i];
  float y = (v - bn[c]) * bn[COUT + c];
  y = y*gamma[c] + beta[c];
  out[i] = y * 0.5f * (1.0f + erff(y * 0.70710678118654752f));
}

extern "C" void kernel_launch(void* const* d_in, const int* in_sizes, int n_in,
                              void* d_out, int out_size, void* d_ws, size_t ws_size,
                              hipStream_t stream){
  const float* xyz   = (const float*)d_in[0];
  const float* x     = (const float*)d_in[1];
  const float* gamma = (const float*)d_in[2];
  const float* beta  = (const float*)d_in[3];
  float* out = (float*)d_out;
  char* ws = (char*)d_ws;
  // workspace layout (all regions fully written before read every launch)
  int*    fps  = (int*)   (ws + 0);        //  32 KB
  int*    knn  = (int*)   (ws + 32768);    //   1 MB
  float*  xs   = (float*) (ws + 1081344);  // 128 KB
  float*  ys   = (float*) (ws + 1212416);
  float*  zs   = (float*) (ws + 1343488);
  float*  d2   = (float*) (ws + 1474560);
  double* parts= (double*)(ws + 1605632);  // 2048*8 doubles
  float*  scal = (float*) (ws + 1736704);  // 4 floats
  float*  bn   = (float*) (ws + 1736768);  // 384 floats

  const int fps_lds = NPTS*16 + 2*8*8;     // 128KB coords table + 16 u64 wave keys
  (void)hipFuncSetAttribute(reinterpret_cast<const void*>(fps_kernel),
                            hipFuncAttributeMaxDynamicSharedMemorySize, fps_lds);

  setup_kernel   <<<dim3((NB*NPTS+255)/256), dim3(256), 0, stream>>>(xyz, xs, ys, zs, d2);
  fps_kernel     <<<dim3(NB),                dim3(512), fps_lds, stream>>>(xyz, fps);
  knn_kernel     <<<dim3(NB*NG/4),           dim3(256), 0, stream>>>(xs, ys, zs, d2, fps, knn);
  stats_kernel   <<<dim3(NB*NG/4),           dim3(256), 0, stream>>>(x, xyz, fps, knn, parts);
  finalize_kernel<<<dim3(1),                 dim3(64),  0, stream>>>(parts, scal);
  main_kernel    <<<dim3(NB*NG/4),           dim3(256), 0, stream>>>(x, xyz, fps, knn, scal, out);
  bn_stats_kernel<<<dim3(COUT),              dim3(256), 0, stream>>>(out, bn);
  final_kernel   <<<dim3((NB*COUT*NG)/256),  dim3(256), 0, stream>>>(bn, gamma, beta, out);
}

// Round 6
// 2432.901 us; speedup vs baseline: 1.2907x; 1.0501x over previous
//
#include <hip/hip_runtime.h>
#include <cstdint>
#include <math.h>

#define NPTS 8192
#define NB 4
#define NG 2048
#define NK 32
#define CIN 96
#define COUT 192

typedef unsigned long long ull;

// ---------------- setup: SoA transpose + |p|^2 (bit-exact vs ref dst2) ----------------
__global__ __launch_bounds__(256) void setup_kernel(const float* __restrict__ xyz,
                                                    float* __restrict__ xs, float* __restrict__ ys,
                                                    float* __restrict__ zs, float* __restrict__ d2){
  int i = blockIdx.x*256 + threadIdx.x;
  if (i >= NB*NPTS) return;
  float x = xyz[3*i+0], y = xyz[3*i+1], z = xyz[3*i+2];
  xs[i]=x; ys[i]=y; zs[i]=z;
  d2[i] = __fadd_rn(__fadd_rn(__fmul_rn(x,x),__fmul_rn(y,y)),__fmul_rn(z,z));
}

// DPP wave reductions (VALU pipe): row_shr 1/2/4/8 + bcast15 + bcast31 -> lane63
template<int CTRL>
__device__ __forceinline__ float dppmaxf(float v){
  int o = __builtin_amdgcn_update_dpp(__float_as_int(v), __float_as_int(v), CTRL, 0xf, 0xf, false);
  return fmaxf(v, __int_as_float(o));
}
template<int CTRL>
__device__ __forceinline__ unsigned dppmaxu(unsigned v){
  unsigned o = (unsigned)__builtin_amdgcn_update_dpp((int)v, (int)v, CTRL, 0xf, 0xf, false);
  return (o > v) ? o : v;
}
__device__ __forceinline__ float wavemaxf(float v){   // result valid in lane 63
  v = dppmaxf<0x111>(v); v = dppmaxf<0x112>(v); v = dppmaxf<0x114>(v);
  v = dppmaxf<0x118>(v); v = dppmaxf<0x142>(v); v = dppmaxf<0x143>(v);
  return v;
}
__device__ __forceinline__ unsigned wavemaxu(unsigned v){  // result valid in lane 63
  v = dppmaxu<0x111>(v); v = dppmaxu<0x112>(v); v = dppmaxu<0x114>(v);
  v = dppmaxu<0x118>(v); v = dppmaxu<0x142>(v); v = dppmaxu<0x143>(v);
  return v;
}

// ---------------- FPS: 512 threads, Morton-sorted points, per-wave bbox pruning -------
// Init: Morton 8x8x8 sort into LDS ctab (coords + orig idx). Wave w owns sorted chunk
// [w*1024,(w+1)*1024) with a tight bbox. Per round: if dist2(center,bbox) > waveMaxD
// *1.0001 the whole wave provably can't change (skip: rewrite cached key). Active path:
// 16-pt update, lowest-orig-idx via constant lowbits u32 max, DPP reduces, lane63 key.
// ONE barrier/round; all waves reduce the 8 keys; coords via ctab broadcast read.
__global__ __launch_bounds__(512,2) void fps_kernel(const float* __restrict__ xyz, int* __restrict__ fps_idx){
#pragma clang fp contract(off)   // selection-critical: no fma contraction anywhere here
  extern __shared__ char smem[];
  float4* ctab = (float4*)smem;                          // 8192*16 = 131072 B
  ull*    keys = (ull*)(smem + 131072);                  // [2][8]
  int*    hist = (int*)(smem + 131072 + 128);            // 512 cells
  float*  bbs  = (float*)(smem + 131072 + 128 + 2048);   // 8 waves * 6
  const int b = blockIdx.x, t = threadIdx.x;
  const int w = t>>6, lane = t&63;
  const float* base = xyz + (size_t)b*NPTS*3;

  // ---- init phase: load originals, global bbox, Morton cells, sort into ctab ----
  float ox[16], oy[16], oz[16];
#pragma unroll
  for (int j=0;j<16;++j){
    int p = t + 512*j;
    ox[j]=base[3*p+0]; oy[j]=base[3*p+1]; oz[j]=base[3*p+2];
  }
  float mnx=ox[0],mxx=ox[0],mny=oy[0],mxy=oy[0],mnz=oz[0],mxz=oz[0];
#pragma unroll
  for (int j=1;j<16;++j){
    mnx=fminf(mnx,ox[j]); mxx=fmaxf(mxx,ox[j]);
    mny=fminf(mny,oy[j]); mxy=fmaxf(mxy,oy[j]);
    mnz=fminf(mnz,oz[j]); mxz=fmaxf(mxz,oz[j]);
  }
#pragma unroll
  for (int off=32; off>0; off>>=1){
    mnx=fminf(mnx,__shfl_xor(mnx,off)); mxx=fmaxf(mxx,__shfl_xor(mxx,off));
    mny=fminf(mny,__shfl_xor(mny,off)); mxy=fmaxf(mxy,__shfl_xor(mxy,off));
    mnz=fminf(mnz,__shfl_xor(mnz,off)); mxz=fmaxf(mxz,__shfl_xor(mxz,off));
  }
  hist[t] = 0;
  if (lane==0){
    bbs[w*6+0]=mnx; bbs[w*6+1]=mxx; bbs[w*6+2]=mny;
    bbs[w*6+3]=mxy; bbs[w*6+4]=mnz; bbs[w*6+5]=mxz;
  }
  if (t==0) fps_idx[b*NG] = 0;
  __syncthreads();
  float gx0=1e30f,gx1=-1e30f,gy0=1e30f,gy1=-1e30f,gz0=1e30f,gz1=-1e30f;
  for (int q=0;q<8;++q){
    gx0=fminf(gx0,bbs[q*6+0]); gx1=fmaxf(gx1,bbs[q*6+1]);
    gy0=fminf(gy0,bbs[q*6+2]); gy1=fmaxf(gy1,bbs[q*6+3]);
    gz0=fminf(gz0,bbs[q*6+4]); gz1=fmaxf(gz1,bbs[q*6+5]);
  }
  const float sxv = 8.0f/fmaxf(gx1-gx0,1e-20f);
  const float syv = 8.0f/fmaxf(gy1-gy0,1e-20f);
  const float szv = 8.0f/fmaxf(gz1-gz0,1e-20f);
  int cell[16];
#pragma unroll
  for (int j=0;j<16;++j){
    int cx = min(7,(int)((ox[j]-gx0)*sxv));
    int cy = min(7,(int)((oy[j]-gy0)*syv));
    int cz = min(7,(int)((oz[j]-gz0)*szv));
    int m = (cx&1) | ((cy&1)<<1) | ((cz&1)<<2)
          | ((cx&2)<<2) | ((cy&2)<<3) | ((cz&2)<<4)
          | ((cx&4)<<4) | ((cy&4)<<5) | ((cz&4)<<6);
    cell[j]=m;
    atomicAdd(&hist[m],1);
  }
  __syncthreads();
  if (t==0){
    int run=0;
    for (int c=0;c<512;++c){ int h=hist[c]; hist[c]=run; run+=h; }
  }
  __syncthreads();
#pragma unroll
  for (int j=0;j<16;++j){
    int pos = atomicAdd(&hist[cell[j]],1);
    ctab[pos] = make_float4(ox[j],oy[j],oz[j], __int_as_float(t+512*j));
  }
  __syncthreads();
  // reload sorted: wave w owns positions w*1024 + j*64 + lane (contiguous chunk)
  float px[16],py[16],pz[16],D[16]; unsigned lowb[16];
  float bx0,bx1,by0,by1,bz0,bz1;
#pragma unroll
  for (int j=0;j<16;++j){
    int pos = (w<<10) + (j<<6) + lane;
    float4 c4 = ctab[pos];
    px[j]=c4.x; py[j]=c4.y; pz[j]=c4.z;
    unsigned orig = (unsigned)__float_as_int(c4.w);
    lowb[j] = ((8191u-orig)<<13) | (unsigned)pos;   // max lowb == (max dist, lowest orig)
    D[j] = 1e10f;                                   // ref init
    if (j==0){ bx0=c4.x; bx1=c4.x; by0=c4.y; by1=c4.y; bz0=c4.z; bz1=c4.z; }
    else {
      bx0=fminf(bx0,c4.x); bx1=fmaxf(bx1,c4.x);
      by0=fminf(by0,c4.y); by1=fmaxf(by1,c4.y);
      bz0=fminf(bz0,c4.z); bz1=fmaxf(bz1,c4.z);
    }
  }
#pragma unroll
  for (int off=32; off>0; off>>=1){
    bx0=fminf(bx0,__shfl_xor(bx0,off)); bx1=fmaxf(bx1,__shfl_xor(bx1,off));
    by0=fminf(by0,__shfl_xor(by0,off)); by1=fmaxf(by1,__shfl_xor(by1,off));
    bz0=fminf(bz0,__shfl_xor(bz0,off)); bz1=fmaxf(bz1,__shfl_xor(bz1,off));
  }

  // ---- serial rounds ----
  float lx=base[0], ly=base[1], lz=base[2];   // seed = point 0
  float Mw = 1e10f;                           // wave's current max D
  unsigned mylow = 0;                         // wave's cached key low32
  for (int it=0; it<NG-1; ++it){
    // exact-safe skip test: LB lower-bounds dist2(center, any owned point);
    // margin 1e-4 rel >> 3e-7 max fp error -> skip only when provably no D changes
    float qx=fminf(fmaxf(lx,bx0),bx1);
    float qy=fminf(fmaxf(ly,by0),by1);
    float qz=fminf(fmaxf(lz,bz0),bz1);
    float ddx=qx-lx, ddy=qy-ly, ddz=qz-lz;
    float LB = (ddx*ddx+ddy*ddy)+ddz*ddz;
    ull* kslot = &keys[(it&1)*8 + w];
    if (LB <= Mw*1.0001f){
      float bd=-1.0f;
#pragma unroll
      for (int j=0;j<16;++j){
        float dx=px[j]-lx, dy=py[j]-ly, dz=pz[j]-lz;
        float d=(dx*dx+dy*dy)+dz*dz;
        float nd=fminf(D[j],d);
        D[j]=nd;
        bd=fmaxf(bd,nd);
      }
      unsigned bl=0;
#pragma unroll
      for (int j=0;j<16;++j){
        unsigned c2 = (lowb[j]>bl)?lowb[j]:bl;
        bl = (D[j]==bd) ? c2 : bl;
      }
      float m = wavemaxf(bd);
      float bdw = __int_as_float(__builtin_amdgcn_readlane(__float_as_int(m),63));
      unsigned cand = (bd==bdw) ? bl : 0u;
      unsigned mu = wavemaxu(cand);
      if (lane==63) *kslot = (((ull)__float_as_uint(bdw))<<32) | (ull)mu;
      Mw = bdw;
      mylow = (unsigned)__builtin_amdgcn_readlane((int)mu,63);
    } else {
      if (lane==63) *kslot = (((ull)__float_as_uint(Mw))<<32) | (ull)mylow;
    }
    __syncthreads();                              // ONE barrier per round
    const ull* kk = keys + (it&1)*8;
    ull k = kk[0];
#pragma unroll
    for (int q=1;q<8;++q){ ull o=kk[q]; if (o>k) k=o; }
    unsigned lw = (unsigned)k;
    float4 c4 = ctab[lw & 0x1FFFu];               // broadcast ds_read_b128
    lx=c4.x; ly=c4.y; lz=c4.z;
    if (t==0) fps_idx[b*NG + it + 1] = (int)(8191u - ((lw>>13)&0x1FFFu));
  }
}

// ---------------- kNN: wave-wide exact top-32 (lexicographic (d,idx)) ----------------
__device__ __forceinline__ bool lexlt(float ad, int ai, float bd, int bi){
  return (ad < bd) || ((ad == bd) && (ai < bi));
}
__device__ __forceinline__ void sort_desc(float& d, int& i, int lane){
#pragma unroll
  for (int k=2;k<=64;k<<=1){
#pragma unroll
    for (int j=k>>1;j>0;j>>=1){
      float od = __shfl_xor(d, j);
      int   oi = __shfl_xor(i, j);
      bool dirUp = (lane & k) != 0;      // flipped -> overall descending
      bool lower = (lane & j) == 0;
      bool less  = lexlt(d,i,od,oi);
      bool keep  = (less == (lower == dirUp));
      if (!keep){ d=od; i=oi; }
    }
  }
}
__device__ __forceinline__ void merge_asc(float& d, int& i, int lane){
#pragma unroll
  for (int j=32;j>0;j>>=1){
    float od = __shfl_xor(d, j);
    int   oi = __shfl_xor(i, j);
    bool lower = (lane & j) == 0;
    bool less  = lexlt(d,i,od,oi);
    bool keep  = (less == lower);
    if (!keep){ d=od; i=oi; }
  }
}

__global__ __launch_bounds__(256) void knn_kernel(const float* __restrict__ xs, const float* __restrict__ ys,
                                                  const float* __restrict__ zs, const float* __restrict__ d2,
                                                  const int* __restrict__ fps_idx, int* __restrict__ knn_out){
  __shared__ float tx[256], ty[256], tz[256], td[256];
  const int tid = threadIdx.x;
  const int wid = tid>>6, lane = tid&63;
  const int pid = blockIdx.x*4 + wid;     // b*NG+g
  const int b = pid >> 11;
  const float* bx = xs + b*NPTS;
  const float* by = ys + b*NPTS;
  const float* bz = zs + b*NPTS;
  const float* bD = d2 + b*NPTS;
  const int fi = fps_idx[pid];
  const float ax = bx[fi], ay = by[fi], az = bz[fi];
  const float src2 = __fadd_rn(__fadd_rn(__fmul_rn(ax,ax),__fmul_rn(ay,ay)),__fmul_rn(az,az));
  float Ad = INFINITY; int Ai = 0x7fffffff;      // sorted-ascending top-64 (1/lane)
  float tau_d = INFINITY; int tau_i = 0x7fffffff; // current exact 32nd smallest
  for (int s=0; s<NPTS/256; ++s){
    __syncthreads();
    int gidx = s*256 + tid;
    tx[tid]=bx[gidx]; ty[tid]=by[gidx]; tz[tid]=bz[gidx]; td[tid]=bD[gidx];
    __syncthreads();
    float m0,m1,m2,m3; int i0,i1,i2,i3;
#define LOADJ(mj, ij, J) { int li = (J)*64 + lane; \
    float dot = __fadd_rn(__fadd_rn(__fmul_rn(ax,tx[li]),__fmul_rn(ay,ty[li])),__fmul_rn(az,tz[li])); \
    mj = __fadd_rn(__fadd_rn(__fmul_rn(-2.0f,dot), src2), td[li]); ij = s*256 + li; }
    LOADJ(m0,i0,0) LOADJ(m1,i1,1) LOADJ(m2,i2,2) LOADJ(m3,i3,3)
#undef LOADJ
    while (true){
      bool any = lexlt(m0,i0,tau_d,tau_i) || lexlt(m1,i1,tau_d,tau_i) ||
                 lexlt(m2,i2,tau_d,tau_i) || lexlt(m3,i3,tau_d,tau_i);
      if (__ballot(any) == 0ull) break;
      float cd = m0; int ci = i0; int sel = 0;
      if (lexlt(m1,i1,cd,ci)){ cd=m1; ci=i1; sel=1; }
      if (lexlt(m2,i2,cd,ci)){ cd=m2; ci=i2; sel=2; }
      if (lexlt(m3,i3,cd,ci)){ cd=m3; ci=i3; sel=3; }
      if      (sel==0) m0=INFINITY;
      else if (sel==1) m1=INFINITY;
      else if (sel==2) m2=INFINITY;
      else             m3=INFINITY;
      sort_desc(cd, ci, lane);                    // new chunk descending
      if (lexlt(cd,ci,Ad,Ai)){ Ad=cd; Ai=ci; }    // elementwise min -> bitonic
      merge_asc(Ad, Ai, lane);                    // re-sort ascending
      tau_d = __shfl(Ad, 31);
      tau_i = __shfl(Ai, 31);
    }
  }
  if (lane < NK) knn_out[pid*NK + lane] = Ai;
}

// ---------------- global stats (fp64 partials per block) ----------------
__global__ __launch_bounds__(256) void stats_kernel(const float* __restrict__ x, const float* __restrict__ xyz,
                                                    const int* __restrict__ fps_idx, const int* __restrict__ knn,
                                                    double* __restrict__ partials){
  const int tid=threadIdx.x, wid=tid>>6, lane=tid&63;
  const int pid = blockIdx.x*4 + wid;
  const int b = pid>>11;
  const int fi = fps_idx[pid];
  const float* xb = x + (size_t)b*NPTS*CIN;
  const float* zb = xyz + (size_t)b*NPTS*3;
  const float lc0 = xb[fi*CIN + lane];
  float lc1 = 0.f; if (lane<32) lc1 = xb[fi*CIN + 64 + lane];
  float czv = 0.f; if (lane<3)  czv = zb[fi*3 + lane];
  double s1=0.0, s2=0.0, a1=0.0, a2=0.0;
  for (int k=0;k<NK;++k){
    int idx = knn[pid*NK + k];
    float d0 = __fsub_rn(xb[idx*CIN + lane], lc0);
    s1 += (double)d0; s2 += (double)d0*(double)d0;
    if (lane<32){
      float d1 = __fsub_rn(xb[idx*CIN + 64 + lane], lc1);
      s1 += (double)d1; s2 += (double)d1*(double)d1;
    }
    if (lane<3){
      float w = __fsub_rn(zb[idx*3 + lane], czv);
      a1 += (double)w; a2 += (double)w*(double)w;
    }
  }
#pragma unroll
  for (int off=32; off>0; off>>=1){ s1 += __shfl_xor(s1,off); s2 += __shfl_xor(s2,off); }
  __shared__ double shx[4][2];
  __shared__ double shz[4][3][2];
  if (lane==0){ shx[wid][0]=s1; shx[wid][1]=s2; }
  if (lane<3){ shz[wid][lane][0]=a1; shz[wid][lane][1]=a2; }
  __syncthreads();
  if (tid==0){
    double u0=0,u1=0;
    for (int w=0;w<4;++w){ u0+=shx[w][0]; u1+=shx[w][1]; }
    double* outp = partials + (size_t)blockIdx.x*8;
    outp[0]=u0; outp[1]=u1;
    for (int axq=0; axq<3; ++axq){
      double v0=0,v1=0;
      for (int w=0;w<4;++w){ v0+=shz[w][axq][0]; v1+=shz[w][axq][1]; }
      outp[2+2*axq]=v0; outp[3+2*axq]=v1;
    }
  }
}

__global__ void finalize_kernel(const double* __restrict__ partials, float* __restrict__ scal){
  const int lane = threadIdx.x;  // 64 threads, 1 wave
  double s1=0,s2=0;
  double z0a=0,z0b=0,z1a=0,z1b=0,z2a=0,z2b=0;
  for (int i=0;i<32;++i){
    const double* p = partials + (size_t)(lane*32+i)*8;   // 32 consecutive blocks -> same b
    s1+=p[0]; s2+=p[1];
    z0a+=p[2]; z0b+=p[3]; z1a+=p[4]; z1b+=p[5]; z2a+=p[6]; z2b+=p[7];
  }
#pragma unroll
  for (int off=32; off>0; off>>=1){ s1+=__shfl_xor(s1,off); s2+=__shfl_xor(s2,off); }
#pragma unroll
  for (int off=8; off>0; off>>=1){
    z0a+=__shfl_xor(z0a,off); z0b+=__shfl_xor(z0b,off);
    z1a+=__shfl_xor(z1a,off); z1b+=__shfl_xor(z1b,off);
    z2a+=__shfl_xor(z2a,off); z2b+=__shfl_xor(z2b,off);
  }
  __shared__ double zb[4][3][2];
  if ((lane&15)==0){
    int b = lane>>4;
    zb[b][0][0]=z0a; zb[b][0][1]=z0b;
    zb[b][1][0]=z1a; zb[b][1][1]=z1b;
    zb[b][2][0]=z2a; zb[b][2][1]=z2b;
  }
  __syncthreads();
  if (lane==0){
    double nx = (double)NB*NG*NK*CIN;
    double varx = (s2 - s1*s1/nx)/(nx-1.0);
    float stdx = (float)sqrt(varx);
    double t1=0,t2=0;
    for (int b=0;b<4;++b) for (int a=0;a<3;++a){ t1+=zb[b][a][0]; t2+=zb[b][a][1]; }
    double nz = (double)NB*NG*NK*3;
    double varz = (t2 - t1*t1/nz)/(nz-1.0);
    float stdz = (float)sqrt(varz);
    float sdiv = stdz + 1e-5f;
    double n2 = (double)NG*NK;
    double acc=0.0;
    for (int b=0;b<4;++b) for (int a=0;a<3;++a){
      double v = (zb[b][a][1] - zb[b][a][0]*zb[b][a][0]/n2)/(n2-1.0);
      acc += sqrt(v);
    }
    float gstd = (float)(acc/12.0) / sdiv;   // std(x4) = std(raw)/(std_xyz+1e-5)
    float sig = 0.26f*(1.0f+gstd) + 1e-6f;
    float blend = 1.0f/(1.0f + expf(-(gstd-0.1f)*10.0f));
    scal[0] = 1.0f/(stdx + 1e-5f);
    scal[1] = 1.0f/sdiv;
    scal[2] = 1.0f/sig;
    scal[3] = blend;
  }
}

// ---------------- main fused kernel: pe + weighting + max/mean over K -> lc in d_out ----------------
__global__ __launch_bounds__(256) void main_kernel(const float* __restrict__ x, const float* __restrict__ xyz,
                                                   const int* __restrict__ fps_idx, const int* __restrict__ knn,
                                                   const float* __restrict__ scal, float* __restrict__ lc_out){
  const int tid=threadIdx.x, wid=tid>>6, lane=tid&63;
  const int pid = blockIdx.x*4 + wid;
  const int b = pid>>11, g = pid&2047;
  const float inv_x = scal[0], inv_z = scal[1], inv_sig = scal[2], blend = scal[3];
  const float omb = 1.0f - blend;
  const int fi = fps_idx[pid];
  const float* xb = x + (size_t)b*NPTS*CIN;
  const float* zb = xyz + (size_t)b*NPTS*3;
  const float cx = zb[fi*3+0], cy = zb[fi*3+1], cz = zb[fi*3+2];
  // lane's 3 channels: c = lane, 64+lane, 128+lane
  const float lcx0 = xb[fi*CIN + lane];
  const float lcx1 = (lane<32) ? xb[fi*CIN + 64 + lane] : xb[fi*CIN + lane - 32];
  const float lcx2 = xb[fi*CIN + 32 + lane];
  // r0: fourier, dim = lane>>5 (0/1), rr = lane&31, freq = rr>>1, odd->cos
  const int dim0 = lane>>5;
  const int rr0 = lane&31;
  const bool cos0 = rr0 & 1;
  const float bs0 = 100.0f / powf(1000.0f, (float)(rr0>>1) * (1.0f/16.0f));
  // r1: lane<32 fourier dim=2; lane>=32 adaptive dim=0, j=lane-32
  const bool cos1 = lane & 1;
  const float bs1 = 100.0f / powf(1000.0f, (float)((lane&31)>>1) * (1.0f/16.0f));
  const float fv1 = (float)(-1.0 + 2.0*(double)(lane-32+1)/33.0);
  // r2: adaptive, cc=32+lane: dim=cc>>5 (1/2), j=cc&31
  const int dim2 = (32+lane)>>5;
  const int j2 = (32+lane)&31;
  const float fv2 = (float)(-1.0 + 2.0*(double)(j2+1)/33.0);

  float mx0=-INFINITY, mx1=-INFINITY, mx2=-INFINITY;
  float sm0=0.f, sm1=0.f, sm2=0.f;
  for (int k=0;k<NK;++k){
    const int idx = knn[pid*NK + k];
    const float p0 = zb[idx*3+0], p1 = zb[idx*3+1], p2v = zb[idx*3+2];
    const float xn0 = (p0-cx)*inv_z, xn1 = (p1-cy)*inv_z, xn2 = (p2v-cz)*inv_z;
    const float xk0 = xb[idx*CIN + lane];
    float xk1 = 0.f; if (lane<32) xk1 = xb[idx*CIN + 64 + lane];
    { // r0
      float v = dim0 ? xn1 : xn0;
      float a = v * bs0;
      float pe = cos0 ? __cosf(a) : __sinf(a);
      float f = (xk0 - lcx0) * inv_x;
      float w = (f + pe) * pe;
      mx0 = fmaxf(mx0, w); sm0 += w;
    }
    { // r1
      float pe, f;
      if (lane < 32){
        float a = xn2 * bs1;
        pe = cos1 ? __cosf(a) : __sinf(a);
        f = (xk1 - lcx1) * inv_x;
      } else {
        float zq = (xn0 - fv1) * inv_sig;
        pe = blend * __expf(-0.5f*zq*zq) + omb * __cosf(zq);
        f = lcx1;   // raw center features (second concat half)
      }
      float w = (f + pe) * pe;
      mx1 = fmaxf(mx1, w); sm1 += w;
    }
    { // r2
      float v = (dim2==1) ? xn1 : xn2;
      float zq = (v - fv2) * inv_sig;
      float pe = blend * __expf(-0.5f*zq*zq) + omb * __cosf(zq);
      float w = (lcx2 + pe) * pe;
      mx2 = fmaxf(mx2, w); sm2 += w;
    }
  }
  const size_t obase = ((size_t)b*COUT)*NG + g;
  lc_out[obase + (size_t)lane*NG]       = mx0 + sm0*(1.0f/32.0f);
  lc_out[obase + (size_t)(64+lane)*NG]  = mx1 + sm1*(1.0f/32.0f);
  lc_out[obase + (size_t)(128+lane)*NG] = mx2 + sm2*(1.0f/32.0f);
}

// ---------------- batch-norm stats (per channel over B,G; ddof=0) ----------------
__global__ __launch_bounds__(256) void bn_stats_kernel(const float* __restrict__ lc, float* __restrict__ bn){
  const int c = blockIdx.x, t = threadIdx.x, lane=t&63, wid=t>>6;
  double s1=0.0, s2=0.0;
  for (int i=t; i<NB*NG; i+=256){
    int b=i>>11, g=i&2047;
    float v = lc[((size_t)(b*COUT)+c)*NG + g];
    s1 += (double)v; s2 += (double)v*(double)v;
  }
#pragma unroll
  for (int off=32; off>0; off>>=1){ s1+=__shfl_xor(s1,off); s2+=__shfl_xor(s2,off); }
  __shared__ double sh1[4], sh2[4];
  if (lane==0){ sh1[wid]=s1; sh2[wid]=s2; }
  __syncthreads();
  if (t==0){
    double a=sh1[0]+sh1[1]+sh1[2]+sh1[3], q=sh2[0]+sh2[1]+sh2[2]+sh2[3];
    double n=(double)(NB*NG);
    double mu=a/n, var=q/n - mu*mu;
    bn[c]=(float)mu;
    bn[COUT+c]=(float)(1.0/sqrt(var + 1e-5));
  }
}

// ---------------- final: BN affine + exact gelu, in-place on d_out ----------------
__global__ __launch_bounds__(256) void final_kernel(const float* __restrict__ bn, const float* __restrict__ gamma,
                                                    const float* __restrict__ beta, float* __restrict__ out){
  int i = blockIdx.x*256 + threadIdx.x;
  int c = (i >> 11) % COUT;
  float v = out[i];
  float y = (v - bn[c]) * bn[COUT + c];
  y = y*gamma[c] + beta[c];
  out[i] = y * 0.5f * (1.0f + erff(y * 0.70710678118654752f));
}

extern "C" void kernel_launch(void* const* d_in, const int* in_sizes, int n_in,
                              void* d_out, int out_size, void* d_ws, size_t ws_size,
                              hipStream_t stream){
  const float* xyz   = (const float*)d_in[0];
  const float* x     = (const float*)d_in[1];
  const float* gamma = (const float*)d_in[2];
  const float* beta  = (const float*)d_in[3];
  float* out = (float*)d_out;
  char* ws = (char*)d_ws;
  // workspace layout (all regions fully written before read every launch)
  int*    fps  = (int*)   (ws + 0);        //  32 KB
  int*    knn  = (int*)   (ws + 32768);    //   1 MB
  float*  xs   = (float*) (ws + 1081344);  // 128 KB
  float*  ys   = (float*) (ws + 1212416);
  float*  zs   = (float*) (ws + 1343488);
  float*  d2   = (float*) (ws + 1474560);
  double* parts= (double*)(ws + 1605632);  // 2048*8 doubles
  float*  scal = (float*) (ws + 1736704);  // 4 floats
  float*  bn   = (float*) (ws + 1736768);  // 384 floats

  const int fps_lds = 131072 + 128 + 2048 + 192;   // ctab + keys + hist + bbox scratch
  (void)hipFuncSetAttribute(reinterpret_cast<const void*>(fps_kernel),
                            hipFuncAttributeMaxDynamicSharedMemorySize, fps_lds);

  setup_kernel   <<<dim3((NB*NPTS+255)/256), dim3(256), 0, stream>>>(xyz, xs, ys, zs, d2);
  fps_kernel     <<<dim3(NB),                dim3(512), fps_lds, stream>>>(xyz, fps);
  knn_kernel     <<<dim3(NB*NG/4),           dim3(256), 0, stream>>>(xs, ys, zs, d2, fps, knn);
  stats_kernel   <<<dim3(NB*NG/4),           dim3(256), 0, stream>>>(x, xyz, fps, knn, parts);
  finalize_kernel<<<dim3(1),                 dim3(64),  0, stream>>>(parts, scal);
  main_kernel    <<<dim3(NB*NG/4),           dim3(256), 0, stream>>>(x, xyz, fps, knn, scal, out);
  bn_stats_kernel<<<dim3(COUT),              dim3(256), 0, stream>>>(out, bn);
  final_kernel   <<<dim3((NB*COUT*NG)/256),  dim3(256), 0, stream>>>(bn, gamma, beta, out);
}